// Round 2
// baseline (5776.321 us; speedup 1.0000x reference)
//
#include <hip/hip_runtime.h>
#include <cstdint>
#include <cstddef>

// ---------------------------------------------------------------------------
// Problem: B=1024, T_X=32, T_V=64, F=128, H=1024, PRED_LEN=64
// 127 sequential LSTM steps (64 enc + 63 dec) + batched output regression.
// Decoder input GEMM folded into weights: W_dec = W_hh + W_ih@W_reg,
//                                         b_dec = (b_ih+b_hh) + W_ih@b_reg.
// out[k] = x_last + sum_{j<=k} (h_j @ W_reg^T + b_reg)   (h_0 = enc final h)
// Vall (the per-step regression outputs) lives in the d_out output region and
// is prefix-scanned in place.
// ---------------------------------------------------------------------------

typedef unsigned short u16;
typedef __bf16 bf16x8 __attribute__((ext_vector_type(8)));
typedef float f32x4 __attribute__((ext_vector_type(4)));

#define DI __device__ __forceinline__

DI u16 f2bf(float x) {                       // round-to-nearest-even f32->bf16
    uint32_t u = __float_as_uint(x);
    u += 0x7fffu + ((u >> 16) & 1u);
    return (u16)(u >> 16);
}
DI float sigm(float x) { return 1.0f / (1.0f + __expf(-x)); }
DI float tanh_(float x) {                    // overflow-safe tanh
    float e = __expf(-2.0f * fabsf(x));
    float r = (1.0f - e) / (1.0f + e);
    return copysignf(r, x);
}

DI void gld16(const void* g, void* l) {      // async global->LDS, 16B/lane
    __builtin_amdgcn_global_load_lds(
        (__attribute__((address_space(1))) void*)(uintptr_t)(g),
        (__attribute__((address_space(3))) void*)(l), 16, 0, 0);
}

DI f32x4 mfma16(bf16x8 a, bf16x8 b, f32x4 c) {
    return __builtin_amdgcn_mfma_f32_16x16x32_bf16(a, b, c, 0, 0, 0);
}

// ---------------------------------------------------------------------------
// Fused LSTM step: gates = Acat @ W^T + bias (bf16 MFMA, f32 acc), then the
// LSTM pointwise update in the epilogue. Block tile: 64 batch x 64 units x
// 4 gates. grid=256 (1 block/CU), 256 threads (4 waves, 2x2).
// LDS is fragment-ordered: 16B chunk index = frag_id*64 + lane, written
// linearly by global_load_lds from pre-permuted global addresses ->
// conflict-free ds_read_b128 on the compute side.
// A-fragment (16x32 MFMA operand): lane = m + 16*(k/8), elem j = k%8.
// B-fragment: lane = n + 16*(k/8).  C/D: col=lane&15, row=(lane>>4)*4+reg.
// ---------------------------------------------------------------------------
__global__ __launch_bounds__(256)
void lstm_step(const u16* __restrict__ A,      // [1024][1152] bf16  (h | v)
               const u16* __restrict__ W,      // [4096][ldw] bf16, row j=g*1024+u
               int ldw, int ntk,               // ntk = K/64 (18 enc, 16 dec)
               const float* __restrict__ bias, // [4096]
               float* __restrict__ cst,        // [1024][1024] f32 cell state
               u16* __restrict__ Aout,         // [1024][1152] bf16 (next step in)
               u16* __restrict__ hall,         // [1024][1024] bf16 or null
               const float* __restrict__ vsrc) // v + (t+1)*128 or null
{
    __shared__ __align__(16) u16 As[64 * 64];    // 8 KB
    __shared__ __align__(16) u16 Bs[256 * 64];   // 32 KB
    const int tid  = threadIdx.x;
    const int lane = tid & 63, wave = tid >> 6;
    const int wm = wave >> 1, wn = wave & 1;
    const int l15 = lane & 15, l4 = lane >> 4;

    // bijective XCD-aware swizzle: both bx tiles of an XCD reuse its L2 slab
    const int id = blockIdx.x;
    const int xcd = id & 7, slot = id >> 3;
    const int bx = xcd * 2 + (slot >> 4);        // unit tile   [0,16)
    const int by = slot & 15;                    // batch tile  [0,16)
    const int u0 = bx << 6, b0 = by << 6;

    f32x4 acc[4][2][2] = {};

    // staging source addresses (frag-ordered chunk -> global element)
    const u16* asrc[2];
#pragma unroll
    for (int i = 0; i < 2; ++i) {
        int fi = i * 4 + wave;                   // [0,8)
        int ks = fi >> 2, mib = fi & 3;
        asrc[i] = A + (size_t)(b0 + mib * 16 + l15) * 1152 + ks * 32 + l4 * 8;
    }
    const u16* bsrc[8];
#pragma unroll
    for (int i = 0; i < 8; ++i) {
        int fi = i * 4 + wave;                   // [0,32)
        int ks = fi >> 4, g = (fi >> 2) & 3, nib = fi & 3;
        bsrc[i] = W + (size_t)(g * 1024 + u0 + nib * 16 + l15) * ldw + ks * 32 + l4 * 8;
    }

    for (int kt = 0; kt < ntk; ++kt) {
#pragma unroll
        for (int i = 0; i < 2; ++i)
            gld16(asrc[i] + kt * 64, (char*)As + ((i * 256 + wave * 64) << 4));
#pragma unroll
        for (int i = 0; i < 8; ++i)
            gld16(bsrc[i] + kt * 64, (char*)Bs + ((i * 256 + wave * 64) << 4));
        __syncthreads();                          // drains vmcnt (gload_lds)
#pragma unroll
        for (int ks = 0; ks < 2; ++ks) {
            bf16x8 af[2];
#pragma unroll
            for (int mi = 0; mi < 2; ++mi)
                af[mi] = *(const bf16x8*)((const char*)As +
                         (((ks * 4 + wm * 2 + mi) * 64 + lane) << 4));
            bf16x8 bfr[4][2];
#pragma unroll
            for (int g = 0; g < 4; ++g)
#pragma unroll
                for (int ni = 0; ni < 2; ++ni)
                    bfr[g][ni] = *(const bf16x8*)((const char*)Bs +
                                 (((ks * 16 + g * 4 + wn * 2 + ni) * 64 + lane) << 4));
#pragma unroll
            for (int g = 0; g < 4; ++g)
#pragma unroll
                for (int mi = 0; mi < 2; ++mi)
#pragma unroll
                    for (int ni = 0; ni < 2; ++ni)
                        acc[g][mi][ni] = mfma16(af[mi], bfr[g][ni], acc[g][mi][ni]);
        }
        __syncthreads();
    }

    // epilogue: LSTM pointwise update
#pragma unroll
    for (int ni = 0; ni < 2; ++ni) {
        const int u = u0 + wn * 32 + ni * 16 + l15;
        const float bi = bias[u], bf = bias[1024 + u], bg = bias[2048 + u], bo = bias[3072 + u];
#pragma unroll
        for (int mi = 0; mi < 2; ++mi) {
#pragma unroll
            for (int j = 0; j < 4; ++j) {
                const int b = b0 + wm * 32 + mi * 16 + l4 * 4 + j;
                const size_t ci = (size_t)b * 1024 + u;
                const float cold = cst[ci];
                const float xi = acc[0][mi][ni][j] + bi;
                const float xf = acc[1][mi][ni][j] + bf;
                const float xg = acc[2][mi][ni][j] + bg;
                const float xo = acc[3][mi][ni][j] + bo;
                const float cn = sigm(xf) * cold + sigm(xi) * tanh_(xg);
                const float hn = sigm(xo) * tanh_(cn);
                cst[ci] = cn;
                const u16 hb = f2bf(hn);
                Aout[(size_t)b * 1152 + u] = hb;
                if (hall) hall[(size_t)b * 1024 + u] = hb;
            }
        }
    }

    // encoder: stage v_{t+1} (bf16) into the v-slot of the next-step input
    if (vsrc != nullptr && bx == 0) {
        for (int s = tid; s < 2048; s += 256) {
            const int bl = s >> 5, f4 = s & 31;
            const float4 vv = *(const float4*)(vsrc + (size_t)(b0 + bl) * 8192 + f4 * 4);
            ushort4 ov = make_ushort4(f2bf(vv.x), f2bf(vv.y), f2bf(vv.z), f2bf(vv.w));
            *(ushort4*)(Aout + (size_t)(b0 + bl) * 1152 + 1024 + f4 * 4) = ov;
        }
    }
}

// ---------------------------------------------------------------------------
// Regression GEMM: C[M][128] = A[M][lda(first 1024 cols)] @ Wreg[128][1024]^T
// 128x128 tile per block, M = grid*128. Same frag-ordered LDS scheme.
// ---------------------------------------------------------------------------
__global__ __launch_bounds__(256)
void gemm_nt(const u16* __restrict__ A, int lda,
             const u16* __restrict__ Bw, float* __restrict__ C)
{
    __shared__ __align__(16) u16 As[128 * 64];   // 16 KB
    __shared__ __align__(16) u16 Bs[128 * 64];   // 16 KB
    const int tid = threadIdx.x, lane = tid & 63, wave = tid >> 6;
    const int wm = wave >> 1, wn = wave & 1;
    const int l15 = lane & 15, l4 = lane >> 4;
    const size_t row0 = (size_t)blockIdx.x * 128;

    f32x4 acc[4][4] = {};
    const u16* asrc[4];
    const u16* bsrc[4];
#pragma unroll
    for (int i = 0; i < 4; ++i) {
        int fi = i * 4 + wave;                   // [0,16)
        int ks = fi >> 3, rib = fi & 7;
        int r = rib * 16 + l15, k = ks * 32 + l4 * 8;
        asrc[i] = A + (row0 + r) * (size_t)lda + k;
        bsrc[i] = Bw + (size_t)r * 1024 + k;
    }
    for (int kt = 0; kt < 16; ++kt) {
#pragma unroll
        for (int i = 0; i < 4; ++i) {
            gld16(asrc[i] + kt * 64, (char*)As + ((i * 256 + wave * 64) << 4));
            gld16(bsrc[i] + kt * 64, (char*)Bs + ((i * 256 + wave * 64) << 4));
        }
        __syncthreads();
#pragma unroll
        for (int ks = 0; ks < 2; ++ks) {
            bf16x8 af[4], bfr[4];
#pragma unroll
            for (int t = 0; t < 4; ++t) {
                af[t]  = *(const bf16x8*)((const char*)As + (((ks * 8 + wm * 4 + t) * 64 + lane) << 4));
                bfr[t] = *(const bf16x8*)((const char*)Bs + (((ks * 8 + wn * 4 + t) * 64 + lane) << 4));
            }
#pragma unroll
            for (int mi = 0; mi < 4; ++mi)
#pragma unroll
                for (int ni = 0; ni < 4; ++ni)
                    acc[mi][ni] = mfma16(af[mi], bfr[ni], acc[mi][ni]);
        }
        __syncthreads();
    }
#pragma unroll
    for (int mi = 0; mi < 4; ++mi)
#pragma unroll
        for (int ni = 0; ni < 4; ++ni) {
            const int r = wm * 64 + mi * 16 + l4 * 4;
            const int cc = wn * 64 + ni * 16 + l15;
#pragma unroll
            for (int j = 0; j < 4; ++j)
                C[(row0 + r + j) * 128 + cc] = acc[mi][ni][j];
        }
}

// --------------------------- small kernels ---------------------------------

// out[k] = x_last + prefix_k(Vall + b_reg); Vall aliases out (in-place safe:
// each element is read once then overwritten by the same thread).
__global__ __launch_bounds__(256)
void scan_out(const float* __restrict__ Vall, const float* __restrict__ x,
              const float* __restrict__ breg, float* __restrict__ out)
{
    const int idx = blockIdx.x * 256 + threadIdx.x;   // 131072 = B*F
    const int b = idx >> 7, f = idx & 127;
    const float br = breg[f];
    float acc = x[(size_t)b * 4096 + 31 * 128 + f];   // x[:, -1, :]
    for (int k = 0; k < 64; ++k) {
        acc += Vall[(size_t)k * 131072 + idx] + br;
        out[(size_t)k * 131072 + idx] = acc;
    }
}

__global__ __launch_bounds__(256)
void transpose_y(const float* __restrict__ y, float* __restrict__ out2)
{
    const int idx = blockIdx.x * 256 + threadIdx.x;   // 2,097,152 float4 slots
    const int f4 = idx & 31;
    const int rest = idx >> 5;
    const int b = rest & 1023, p = rest >> 10;
    const float4 vv = *(const float4*)(y + ((size_t)b * 64 + p) * 128 + f4 * 4);
    *(float4*)(out2 + ((size_t)p * 1024 + b) * 128 + f4 * 4) = vv;
}

__global__ __launch_bounds__(256)
void prep_bias(const float* __restrict__ bih, const float* __restrict__ bhh,
               const float* __restrict__ Wih, const float* __restrict__ breg,
               float* __restrict__ bcomb, float* __restrict__ bdec)
{
    const int j = blockIdx.x * 256 + threadIdx.x;     // 4096
    const float b = bih[j] + bhh[j];
    bcomb[j] = b;
    float acc = b;
    for (int f = 0; f < 128; ++f) acc += Wih[(size_t)j * 128 + f] * breg[f];
    bdec[j] = acc;
}

__global__ __launch_bounds__(256)
void conv_wcat(const float* __restrict__ Whh, const float* __restrict__ Wih,
               u16* __restrict__ Wcat)
{
    const int idx = blockIdx.x * 256 + threadIdx.x;   // 4096*288 float4 slots
    const int j = idx / 288, r = idx % 288;
    const float4 vv = (r < 256)
        ? *(const float4*)(Whh + (size_t)j * 1024 + r * 4)
        : *(const float4*)(Wih + (size_t)j * 128 + (r - 256) * 4);
    ushort4 ov = make_ushort4(f2bf(vv.x), f2bf(vv.y), f2bf(vv.z), f2bf(vv.w));
    *(ushort4*)(Wcat + (size_t)j * 1152 + r * 4) = ov;
}

__global__ __launch_bounds__(256)
void conv_wreg(const float* __restrict__ Wreg, u16* __restrict__ Wregb)
{
    const int idx = blockIdx.x * 256 + threadIdx.x;   // 32768 float4 slots
    const float4 vv = *(const float4*)(Wreg + (size_t)idx * 4);
    ushort4 ov = make_ushort4(f2bf(vv.x), f2bf(vv.y), f2bf(vv.z), f2bf(vv.w));
    *(ushort4*)(Wregb + (size_t)idx * 4) = ov;
}

// W_dec = W_hh + W_ih @ W_reg  (f32 compute, bf16 store). 256 blocks.
__global__ __launch_bounds__(256)
void prep_wdec(const float* __restrict__ Whh, const float* __restrict__ Wih,
               const float* __restrict__ Wreg, u16* __restrict__ Wdec)
{
    __shared__ float wih[64][128];                    // 32 KB
    const int bid = blockIdx.x;
    const int jt = bid >> 2, ut = bid & 3;
    const int j0 = jt * 64;
    const int u = ut * 256 + threadIdx.x;
    for (int s = threadIdx.x; s < 64 * 128; s += 256)
        wih[s >> 7][s & 127] = Wih[(size_t)(j0 + (s >> 7)) * 128 + (s & 127)];
    __syncthreads();
    float acc[64];
#pragma unroll
    for (int j = 0; j < 64; ++j) acc[j] = Whh[(size_t)(j0 + j) * 1024 + u];
    for (int f = 0; f < 128; ++f) {
        const float wr = Wreg[(size_t)f * 1024 + u];
#pragma unroll
        for (int j = 0; j < 64; ++j) acc[j] += wih[j][f] * wr;
    }
#pragma unroll
    for (int j = 0; j < 64; ++j) Wdec[(size_t)(j0 + j) * 1024 + u] = f2bf(acc[j]);
}

__global__ __launch_bounds__(256)
void init_acat(const float* __restrict__ v, u16* __restrict__ Acat)
{
    const int idx = blockIdx.x * 256 + threadIdx.x;   // 32768 float4 slots
    const int b = idx >> 5, f4 = idx & 31;
    const float4 vv = *(const float4*)(v + (size_t)b * 8192 + f4 * 4);
    ushort4 ov = make_ushort4(f2bf(vv.x), f2bf(vv.y), f2bf(vv.z), f2bf(vv.w));
    *(ushort4*)(Acat + (size_t)b * 1152 + 1024 + f4 * 4) = ov;
}

// ---------------------------------------------------------------------------

extern "C" void kernel_launch(void* const* d_in, const int* in_sizes, int n_in,
                              void* d_out, int out_size, void* d_ws, size_t ws_size,
                              hipStream_t stream)
{
    const float* x    = (const float*)d_in[0];
    const float* y    = (const float*)d_in[1];
    const float* v    = (const float*)d_in[2];
    const float* Wih  = (const float*)d_in[3];
    const float* Whh  = (const float*)d_in[4];
    const float* bih  = (const float*)d_in[5];
    const float* bhh  = (const float*)d_in[6];
    const float* Wreg = (const float*)d_in[7];
    const float* breg = (const float*)d_in[8];
    float* out = (float*)d_out;
    char* ws = (char*)d_ws;

    u16*   Wcat  = (u16*)(ws + 0);              //  9,437,184  [4096][1152] bf16
    u16*   Wdec  = (u16*)(ws + 9437184);        //  8,388,608  [4096][1024] bf16
    u16*   Wregb = (u16*)(ws + 17825792);       //    262,144  [128][1024] bf16
    float* bcomb = (float*)(ws + 18087936);     //     16,384
    float* bdec  = (float*)(ws + 18104320);     //     16,384
    u16*   Ac0   = (u16*)(ws + 18120704);       //  2,359,296  [1024][1152] bf16
    u16*   Ac1   = (u16*)(ws + 20480000);       //  2,359,296
    float* cst   = (float*)(ws + 22839296);     //  4,194,304  [1024][1024] f32
    u16*   Hall  = (u16*)(ws + 27033600);       //134,217,728  [64][1024][1024] bf16
    float* Vall  = out;                         // aliases output region (33.5 MB)
    u16* Ac[2] = {Ac0, Ac1};

    // Hall (batched final GEMM) only if the workspace is big enough.
    const bool batched = ws_size >= (size_t)27033600 + 134217728;

    hipMemsetAsync(cst, 0, 4194304, stream);    // c0 = 0
    hipMemsetAsync(Ac0, 0, 2359296, stream);    // h0 = 0 (bf16 zero bits)
    prep_bias<<<16, 256, 0, stream>>>(bih, bhh, Wih, breg, bcomb, bdec);
    conv_wcat<<<4608, 256, 0, stream>>>(Whh, Wih, Wcat);
    conv_wreg<<<128, 256, 0, stream>>>(Wreg, Wregb);
    prep_wdec<<<256, 256, 0, stream>>>(Whh, Wih, Wreg, Wdec);
    init_acat<<<128, 256, 0, stream>>>(v, Ac0);
    transpose_y<<<8192, 256, 0, stream>>>(y, out + 8388608);

    // encoder: 64 steps, K = 1152 ([h | v_t] @ [W_hh | W_ih]^T)
    for (int t = 0; t < 64; ++t) {
        lstm_step<<<256, 256, 0, stream>>>(
            Ac[t & 1], Wcat, 1152, 18, bcomb, cst, Ac[(t + 1) & 1],
            (batched && t == 63) ? Hall : (u16*)nullptr,
            (t < 63) ? (v + (size_t)(t + 1) * 128) : (const float*)nullptr);
    }
    if (!batched)   // Vall[0] = h_0 @ W_reg^T
        gemm_nt<<<8, 256, 0, stream>>>(Ac[0], 1152, Wregb, Vall);

    // decoder: 63 steps, K = 1024 (h @ W_dec^T)
    for (int k = 1; k < 64; ++k) {
        lstm_step<<<256, 256, 0, stream>>>(
            Ac[(k + 1) & 1], Wdec, 1024, 16, bdec, cst, Ac[k & 1],
            batched ? (Hall + (size_t)k * 1048576) : (u16*)nullptr,
            (const float*)nullptr);
        if (!batched)   // Vall[k] = h_k @ W_reg^T
            gemm_nt<<<8, 256, 0, stream>>>(Ac[k & 1], 1152, Wregb,
                                           Vall + (size_t)k * 131072);
    }
    if (batched)    // Vall[k][b][:] = h_k @ W_reg^T  (one GEMM, M=65536)
        gemm_nt<<<512, 256, 0, stream>>>(Hall, 1024, Wregb, Vall);

    // out[k] = x_last + prefix_sum(Vall + b_reg)
    scan_out<<<512, 256, 0, stream>>>(Vall, x, breg, out);
}

// Round 4
// 3915.789 us; speedup vs baseline: 1.4751x; 1.4751x over previous
//
#include <hip/hip_runtime.h>
#include <cstdint>
#include <cstddef>

// ---------------------------------------------------------------------------
// B=1024, T_X=32, T_V=64, F=128, H=1024, PRED_LEN=64
// 127 sequential LSTM steps (64 enc + 63 dec) + batched output regression.
// W_dec = W_hh + W_ih@W_reg ; b_dec = (b_ih+b_hh) + W_ih@b_reg.
// out[k] = x_last + sum_{j<=k} (h_j @ W_reg^T + b_reg)   (h_0 = enc final h)
// Vall lives in the d_out region and is prefix-scanned in place.
// ---------------------------------------------------------------------------

typedef unsigned short u16;
typedef __bf16 bf16x8 __attribute__((ext_vector_type(8)));
typedef float f32x4 __attribute__((ext_vector_type(4)));

#define DI __device__ __forceinline__

DI u16 f2bf(float x) {                       // round-to-nearest-even f32->bf16
    uint32_t u = __float_as_uint(x);
    u += 0x7fffu + ((u >> 16) & 1u);
    return (u16)(u >> 16);
}
DI float sigm(float x) { return 1.0f / (1.0f + __expf(-x)); }
DI float tanh_(float x) {                    // overflow-safe tanh
    float e = __expf(-2.0f * fabsf(x));
    float r = (1.0f - e) / (1.0f + e);
    return copysignf(r, x);
}

DI void gld16(const void* g, void* l) {      // async global->LDS, 16B/lane
    __builtin_amdgcn_global_load_lds(
        (__attribute__((address_space(1))) void*)(uintptr_t)(g),
        (__attribute__((address_space(3))) void*)(l), 16, 0, 0);
}

DI f32x4 mfma16(bf16x8 a, bf16x8 b, f32x4 c) {
    return __builtin_amdgcn_mfma_f32_16x16x32_bf16(a, b, c, 0, 0, 0);
}

// ---------------------------------------------------------------------------
// Fused LSTM step v2. Tile: 64 batch x 32 units x 4 gates (M=64, N=128 cols).
// Grid 512 (2 blocks/CU), 512 threads = 8 waves (4m x 2n) -> 4 waves/SIMD.
// Double-buffered LDS (48 KB) + 2-phase prefetch: STAGE(kt+1) issued before
// COMPUTE(kt); single __syncthreads (vmcnt+lgkm drain) per K-tile.
// LDS is fragment-ordered 1KB chunks (chunk = frag, linear lane*16B inside),
// staged by global_load_lds from pre-permuted global addresses.
// A-frag chunk fi = ks*4 + mfrag ; B-frag chunk fi = ks*8 + uhalf*4 + gate.
// C/D layout: col = lane&15, row = (lane>>4)*4 + reg.
// ---------------------------------------------------------------------------
__global__ __launch_bounds__(512, 4)
void lstm_step(const u16* __restrict__ A,      // [1024][1152] bf16 (h | v)
               const u16* __restrict__ W,      // [4096][ldw] bf16, row j=g*1024+u
               int ldw, int kt0, int ntk,      // K-tiles [kt0, ntk)
               const float* __restrict__ bias, // [4096]
               float* __restrict__ cst,        // [1024][1024] f32 cell state
               u16* __restrict__ Aout,         // [1024][1152] bf16
               u16* __restrict__ hall,         // [1024][1024] bf16 or null
               const float* __restrict__ vsrc) // v + (t+1)*128 or null
{
    __shared__ __align__(16) u16 As[2][4096];    // 2 x 8 KB  (8 chunks)
    __shared__ __align__(16) u16 Bs[2][8192];    // 2 x 16 KB (16 chunks)
    const int tid  = threadIdx.x;
    const int lane = tid & 63, wave = tid >> 6;  // 8 waves
    const int wm = wave >> 1, wn = wave & 1;     // 4m x 2n
    const int l15 = lane & 15, l4 = lane >> 4;

    // bijective XCD-aware swizzle: 4 bx unit-tiles pinned per XCD L2
    const int id = blockIdx.x;
    const int xcd = id & 7, slot = id >> 3;      // slot in [0,64)
    const int bx = xcd * 4 + (slot >> 4);        // [0,32)
    const int by = slot & 15;                    // [0,16)
    const int u0 = bx << 5, b0 = by << 6;

    f32x4 acc[4] = {};                           // one f32x4 per gate

    // staging sources (this wave's chunks)
    const u16* asrc = A + (size_t)(b0 + (wave & 3) * 16 + l15) * 1152
                        + (wave >> 2) * 32 + l4 * 8;
    const u16* bsrc[2];
#pragma unroll
    for (int i = 0; i < 2; ++i) {
        const int fi = i * 8 + wave;             // [0,16)
        const int ks = fi >> 3, uh = (fi >> 2) & 1, g = fi & 3;
        bsrc[i] = W + (size_t)(g * 1024 + u0 + uh * 16 + l15) * ldw
                    + ks * 32 + l4 * 8;
    }

#define STAGE(kt, buf)                                                        \
    {                                                                         \
        const size_t ko = (size_t)(kt) * 64;                                  \
        gld16(asrc + ko, (char*)&As[buf][0] + (wave << 10));                  \
        gld16(bsrc[0] + ko, (char*)&Bs[buf][0] + (wave << 10));               \
        gld16(bsrc[1] + ko, (char*)&Bs[buf][0] + ((8 + wave) << 10));         \
    }

    STAGE(kt0, 0);
    __syncthreads();
    int buf = 0;
    for (int kt = kt0; kt < ntk; ++kt) {
        if (kt + 1 < ntk) STAGE(kt + 1, buf ^ 1);
#pragma unroll
        for (int ks = 0; ks < 2; ++ks) {
            const bf16x8 af = *(const bf16x8*)((const char*)&As[buf][0] +
                              (((ks * 4 + wm) * 64 + lane) << 4));
            bf16x8 bfr[4];
#pragma unroll
            for (int g = 0; g < 4; ++g)
                bfr[g] = *(const bf16x8*)((const char*)&Bs[buf][0] +
                         (((ks * 8 + wn * 4 + g) * 64 + lane) << 4));
#pragma unroll
            for (int g = 0; g < 4; ++g)
                acc[g] = mfma16(af, bfr[g], acc[g]);
        }
        __syncthreads();                         // drains vmcnt of prefetch too
        buf ^= 1;
    }
#undef STAGE

    // epilogue: LSTM pointwise update
    const int u = u0 + wn * 16 + l15;
    const float bi = bias[u],        bff = bias[1024 + u],
                bg = bias[2048 + u], bo  = bias[3072 + u];
    const int brow = b0 + wm * 16 + l4 * 4;
#pragma unroll
    for (int j = 0; j < 4; ++j) {
        const int b = brow + j;
        const size_t ci = (size_t)b * 1024 + u;
        const float cold = cst[ci];
        const float xi = acc[0][j] + bi;
        const float xf = acc[1][j] + bff;
        const float xg = acc[2][j] + bg;
        const float xo = acc[3][j] + bo;
        const float cn = sigm(xf) * cold + sigm(xi) * tanh_(xg);
        const float hn = sigm(xo) * tanh_(cn);
        cst[ci] = cn;
        const u16 hb = f2bf(hn);
        Aout[(size_t)b * 1152 + u] = hb;
        if (hall) hall[(size_t)b * 1024 + u] = hb;
    }

    // encoder: stage v_{t+1} (bf16) into the v-slot of the next-step input
    if (vsrc != nullptr && bx == 0) {
        for (int s = tid; s < 2048; s += 512) {
            const int bl = s >> 5, f4 = s & 31;
            const float4 vv = *(const float4*)(vsrc + (size_t)(b0 + bl) * 8192 + f4 * 4);
            ushort4 ov = make_ushort4(f2bf(vv.x), f2bf(vv.y), f2bf(vv.z), f2bf(vv.w));
            *(ushort4*)(Aout + (size_t)(b0 + bl) * 1152 + 1024 + f4 * 4) = ov;
        }
    }
}

// ---------------------------------------------------------------------------
// Regression GEMM: C[M][128] = A[M][lda(first 1024 cols)] @ Wreg[128][1024]^T
// 128x128 tile per block, M = grid*128.
// ---------------------------------------------------------------------------
__global__ __launch_bounds__(256)
void gemm_nt(const u16* __restrict__ A, int lda,
             const u16* __restrict__ Bw, float* __restrict__ C)
{
    __shared__ __align__(16) u16 As[128 * 64];   // 16 KB
    __shared__ __align__(16) u16 Bs[128 * 64];   // 16 KB
    const int tid = threadIdx.x, lane = tid & 63, wave = tid >> 6;
    const int wm = wave >> 1, wn = wave & 1;
    const int l15 = lane & 15, l4 = lane >> 4;
    const size_t row0 = (size_t)blockIdx.x * 128;

    f32x4 acc[4][4] = {};
    const u16* asrc[4];
    const u16* bsrc[4];
#pragma unroll
    for (int i = 0; i < 4; ++i) {
        int fi = i * 4 + wave;                   // [0,16)
        int ks = fi >> 3, rib = fi & 7;
        int r = rib * 16 + l15, k = ks * 32 + l4 * 8;
        asrc[i] = A + (row0 + r) * (size_t)lda + k;
        bsrc[i] = Bw + (size_t)r * 1024 + k;
    }
    for (int kt = 0; kt < 16; ++kt) {
#pragma unroll
        for (int i = 0; i < 4; ++i) {
            gld16(asrc[i] + kt * 64, (char*)As + ((i * 256 + wave * 64) << 4));
            gld16(bsrc[i] + kt * 64, (char*)Bs + ((i * 256 + wave * 64) << 4));
        }
        __syncthreads();
#pragma unroll
        for (int ks = 0; ks < 2; ++ks) {
            bf16x8 af[4], bfr[4];
#pragma unroll
            for (int t = 0; t < 4; ++t) {
                af[t]  = *(const bf16x8*)((const char*)As + (((ks * 8 + wm * 4 + t) * 64 + lane) << 4));
                bfr[t] = *(const bf16x8*)((const char*)Bs + (((ks * 8 + wn * 4 + t) * 64 + lane) << 4));
            }
#pragma unroll
            for (int mi = 0; mi < 4; ++mi)
#pragma unroll
                for (int ni = 0; ni < 4; ++ni)
                    acc[mi][ni] = mfma16(af[mi], bfr[ni], acc[mi][ni]);
        }
        __syncthreads();
    }
#pragma unroll
    for (int mi = 0; mi < 4; ++mi)
#pragma unroll
        for (int ni = 0; ni < 4; ++ni) {
            const int r = wm * 64 + mi * 16 + l4 * 4;
            const int cc = wn * 64 + ni * 16 + l15;
#pragma unroll
            for (int j = 0; j < 4; ++j)
                C[(row0 + r + j) * 128 + cc] = acc[mi][ni][j];
        }
}

// --------------------------- small kernels ---------------------------------

// out[k] = x_last + prefix_k(Vall + b_reg); Vall aliases out (in-place safe).
__global__ __launch_bounds__(256)
void scan_out(const float* __restrict__ Vall, const float* __restrict__ x,
              const float* __restrict__ breg, float* __restrict__ out)
{
    const int idx = blockIdx.x * 256 + threadIdx.x;   // 131072 = B*F
    const int b = idx >> 7, f = idx & 127;
    const float br = breg[f];
    float acc = x[(size_t)b * 4096 + 31 * 128 + f];   // x[:, -1, :]
    for (int k = 0; k < 64; ++k) {
        acc += Vall[(size_t)k * 131072 + idx] + br;
        out[(size_t)k * 131072 + idx] = acc;
    }
}

__global__ __launch_bounds__(256)
void transpose_y(const float* __restrict__ y, float* __restrict__ out2)
{
    const int idx = blockIdx.x * 256 + threadIdx.x;   // 2,097,152 float4 slots
    const int f4 = idx & 31;
    const int rest = idx >> 5;
    const int b = rest & 1023, p = rest >> 10;
    const float4 vv = *(const float4*)(y + ((size_t)b * 64 + p) * 128 + f4 * 4);
    *(float4*)(out2 + ((size_t)p * 1024 + b) * 128 + f4 * 4) = vv;
}

__global__ __launch_bounds__(256)
void conv_wcat(const float* __restrict__ Whh, const float* __restrict__ Wih,
               u16* __restrict__ Wcat)
{
    const int idx = blockIdx.x * 256 + threadIdx.x;   // 4096*288 float4 slots
    const int j = idx / 288, r = idx % 288;
    const float4 vv = (r < 256)
        ? *(const float4*)(Whh + (size_t)j * 1024 + r * 4)
        : *(const float4*)(Wih + (size_t)j * 128 + (r - 256) * 4);
    ushort4 ov = make_ushort4(f2bf(vv.x), f2bf(vv.y), f2bf(vv.z), f2bf(vv.w));
    *(ushort4*)(Wcat + (size_t)j * 1152 + r * 4) = ov;
}

__global__ __launch_bounds__(256)
void conv_wreg(const float* __restrict__ Wreg, u16* __restrict__ Wregb)
{
    const int idx = blockIdx.x * 256 + threadIdx.x;   // 32768 float4 slots
    const float4 vv = *(const float4*)(Wreg + (size_t)idx * 4);
    ushort4 ov = make_ushort4(f2bf(vv.x), f2bf(vv.y), f2bf(vv.z), f2bf(vv.w));
    *(ushort4*)(Wregb + (size_t)idx * 4) = ov;
}

// W_dec = W_hh + W_ih @ W_reg (f32, bf16 store); also bcomb = b_ih+b_hh and
// b_dec = bcomb + W_ih @ b_reg. Grid 1024: 256 j-tiles x 4 u-tiles; 16 acc
// registers per thread (no spill).
__global__ __launch_bounds__(256)
void prep_wdec(const float* __restrict__ Whh, const float* __restrict__ Wih,
               const float* __restrict__ Wreg, const float* __restrict__ bih,
               const float* __restrict__ bhh, const float* __restrict__ breg,
               u16* __restrict__ Wdec, float* __restrict__ bcomb,
               float* __restrict__ bdec)
{
    __shared__ float wih[16][128];                    // 8 KB
    const int jt = blockIdx.x >> 2, ut = blockIdx.x & 3;
    const int j0 = jt * 16;
    const int u = ut * 256 + threadIdx.x;
    for (int s = threadIdx.x; s < 2048; s += 256)
        wih[s >> 7][s & 127] = Wih[(size_t)(j0 + (s >> 7)) * 128 + (s & 127)];
    __syncthreads();
    float acc[16];
#pragma unroll
    for (int j = 0; j < 16; ++j) acc[j] = Whh[(size_t)(j0 + j) * 1024 + u];
    for (int f = 0; f < 128; ++f) {
        const float wr = Wreg[(size_t)f * 1024 + u];
#pragma unroll
        for (int j = 0; j < 16; ++j) acc[j] += wih[j][f] * wr;
    }
#pragma unroll
    for (int j = 0; j < 16; ++j)
        Wdec[(size_t)(j0 + j) * 1024 + u] = f2bf(acc[j]);
    if (ut == 0 && threadIdx.x < 16) {
        const int j = j0 + threadIdx.x;
        float a = bih[j] + bhh[j];
        bcomb[j] = a;
        for (int f = 0; f < 128; ++f) a += wih[threadIdx.x][f] * breg[f];
        bdec[j] = a;
    }
}

__global__ __launch_bounds__(256)
void init_acat(const float* __restrict__ v, u16* __restrict__ Acat)
{
    const int idx = blockIdx.x * 256 + threadIdx.x;   // 32768 float4 slots
    const int b = idx >> 5, f4 = idx & 31;
    const float4 vv = *(const float4*)(v + (size_t)b * 8192 + f4 * 4);
    ushort4 ov = make_ushort4(f2bf(vv.x), f2bf(vv.y), f2bf(vv.z), f2bf(vv.w));
    *(ushort4*)(Acat + (size_t)b * 1152 + 1024 + f4 * 4) = ov;
}

// ---------------------------------------------------------------------------

extern "C" void kernel_launch(void* const* d_in, const int* in_sizes, int n_in,
                              void* d_out, int out_size, void* d_ws, size_t ws_size,
                              hipStream_t stream)
{
    const float* x    = (const float*)d_in[0];
    const float* y    = (const float*)d_in[1];
    const float* v    = (const float*)d_in[2];
    const float* Wih  = (const float*)d_in[3];
    const float* Whh  = (const float*)d_in[4];
    const float* bih  = (const float*)d_in[5];
    const float* bhh  = (const float*)d_in[6];
    const float* Wreg = (const float*)d_in[7];
    const float* breg = (const float*)d_in[8];
    float* out = (float*)d_out;
    char* ws = (char*)d_ws;

    u16*   Wcat  = (u16*)(ws + 0);              //  9,437,184  [4096][1152] bf16
    u16*   Wdec  = (u16*)(ws + 9437184);        //  8,388,608  [4096][1024] bf16
    u16*   Wregb = (u16*)(ws + 17825792);       //    262,144  [128][1024] bf16
    float* bcomb = (float*)(ws + 18087936);     //     16,384
    float* bdec  = (float*)(ws + 18104320);     //     16,384
    u16*   Ac0   = (u16*)(ws + 18120704);       //  2,359,296  [1024][1152] bf16
    u16*   Ac1   = (u16*)(ws + 20480000);       //  2,359,296
    float* cst   = (float*)(ws + 22839296);     //  4,194,304  [1024][1024] f32
    u16*   Hall  = (u16*)(ws + 27033600);       //134,217,728  [64][1024][1024] bf16
    float* Vall  = out;                         // aliases output region (33.5 MB)
    u16* Ac[2] = {Ac0, Ac1};

    const bool batched = ws_size >= (size_t)27033600 + 134217728;

    hipMemsetAsync(cst, 0, 4194304, stream);    // c0 = 0
    hipMemsetAsync(Ac0, 0, 2359296, stream);    // h0 = 0 (bf16 zero bits)
    prep_wdec<<<1024, 256, 0, stream>>>(Whh, Wih, Wreg, bih, bhh, breg,
                                        Wdec, bcomb, bdec);
    conv_wcat<<<4608, 256, 0, stream>>>(Whh, Wih, Wcat);
    conv_wreg<<<128, 256, 0, stream>>>(Wreg, Wregb);
    init_acat<<<128, 256, 0, stream>>>(v, Ac0);
    transpose_y<<<8192, 256, 0, stream>>>(y, out + 8388608);

    // encoder: 64 steps, K = 1152 ([h | v_t] @ [W_hh | W_ih]^T).
    // t=0 has h==0, so only the v columns (K-tiles 16..17) are computed.
    for (int t = 0; t < 64; ++t) {
        lstm_step<<<512, 512, 0, stream>>>(
            Ac[t & 1], Wcat, 1152, (t == 0) ? 16 : 0, 18, bcomb, cst,
            Ac[(t + 1) & 1],
            (batched && t == 63) ? Hall : (u16*)nullptr,
            (t < 63) ? (v + (size_t)(t + 1) * 128) : (const float*)nullptr);
    }
    if (!batched)   // Vall[0] = h_0 @ W_reg^T
        gemm_nt<<<8, 256, 0, stream>>>(Ac[0], 1152, Wregb, Vall);

    // decoder: 63 steps, K = 1024 (h @ W_dec^T)
    for (int k = 1; k < 64; ++k) {
        lstm_step<<<512, 512, 0, stream>>>(
            Ac[(k + 1) & 1], Wdec, 1024, 0, 16, bdec, cst, Ac[k & 1],
            batched ? (Hall + (size_t)k * 1048576) : (u16*)nullptr,
            (const float*)nullptr);
        if (!batched)
            gemm_nt<<<8, 256, 0, stream>>>(Ac[k & 1], 1152, Wregb,
                                           Vall + (size_t)k * 131072);
    }
    if (batched)    // Vall[k][b][:] = h_k @ W_reg^T  (one GEMM, M=65536)
        gemm_nt<<<512, 256, 0, stream>>>(Hall, 1024, Wregb, Vall);

    // out[k] = x_last + prefix_sum(Vall + b_reg)
    scan_out<<<512, 256, 0, stream>>>(Vall, x, breg, out);
}

// Round 5
// 3548.221 us; speedup vs baseline: 1.6279x; 1.1036x over previous
//
#include <hip/hip_runtime.h>
#include <cstdint>
#include <cstddef>

// ---------------------------------------------------------------------------
// B=1024, T_X=32, T_V=64, F=128, H=1024, PRED_LEN=64
// 127 sequential LSTM steps (64 enc + 63 dec) + batched output regression.
// W_dec = W_hh + W_ih@W_reg ; b_dec = (b_ih+b_hh) + W_ih@b_reg.
// out[k] = x_last + sum_{j<=k} (h_j @ W_reg^T + b_reg)   (h_0 = enc final h)
// Vall lives in the d_out region and is prefix-scanned in place.
// ---------------------------------------------------------------------------

typedef unsigned short u16;
typedef __bf16 bf16x8 __attribute__((ext_vector_type(8)));
typedef float f32x4 __attribute__((ext_vector_type(4)));

#define DI __device__ __forceinline__

DI u16 f2bf(float x) {                       // round-to-nearest-even f32->bf16
    uint32_t u = __float_as_uint(x);
    u += 0x7fffu + ((u >> 16) & 1u);
    return (u16)(u >> 16);
}
DI float sigm(float x) { return 1.0f / (1.0f + __expf(-x)); }
DI float tanh_(float x) {                    // overflow-safe tanh
    float e = __expf(-2.0f * fabsf(x));
    float r = (1.0f - e) / (1.0f + e);
    return copysignf(r, x);
}

DI void gld16(const void* g, void* l) {      // async global->LDS, 16B/lane
    __builtin_amdgcn_global_load_lds(
        (__attribute__((address_space(1))) void*)(uintptr_t)(g),
        (__attribute__((address_space(3))) void*)(l), 16, 0, 0);
}

DI f32x4 mfma16(bf16x8 a, bf16x8 b, f32x4 c) {
    return __builtin_amdgcn_mfma_f32_16x16x32_bf16(a, b, c, 0, 0, 0);
}

// ---------------------------------------------------------------------------
// Fused LSTM step v3. Tile: 128 batch x 32 units x 4 gates per block.
// Grid 256 (1 block/CU), 256 threads = 4 waves (2m x 2n); wave tile 64x64
// (mi=4, ni=4 -> 8 ds_read_b128 : 16 MFMA per ks, 2.5x less LDS traffic
// than v2's 10:8). Triple-buffered LDS (96 KB), 2-tile-deep prefetch with
// counted s_waitcnt vmcnt(8) (vmcnt(0) only on the last tile) + raw
// s_barrier: loads stay in flight across barriers (T3/T4).
// LDS chunk layout per buf (32 KB): chunks 0..15 = A frags (mf*2+ks),
// 16..31 = B frags (nf*2+ks), nf = gate*2 + unit_half; chunk = 1 KB,
// lane-linear (gld16 dest = base + lane*16).
// MFMA frags: A/B lane = idx + 16*(k/8); C/D col=lane&15, row=(lane>>4)*4+reg.
// ---------------------------------------------------------------------------
__global__ __launch_bounds__(256, 1)
void lstm_step(const u16* __restrict__ A,      // [1024][1152] bf16 (h | v)
               const u16* __restrict__ W,      // [4096][ldw] bf16, row j=g*1024+u
               int ldw, int kt0, int ntk,      // K-tiles [kt0, ntk)
               const float* __restrict__ bias, // [4096]
               float* __restrict__ cst,        // [1024][1024] f32 cell state
               u16* __restrict__ Aout,         // [1024][1152] bf16
               u16* __restrict__ hall,         // [1024][1024] bf16 or null
               const float* __restrict__ vsrc) // v + (t+1)*128 or null
{
    __shared__ __align__(16) u16 S[3][16384];    // 3 x 32 KB
    const int tid  = threadIdx.x;
    const int lane = tid & 63, wave = tid >> 6;  // 4 waves
    const int wm = wave >> 1, wn = wave & 1;     // 2m x 2n
    const int l15 = lane & 15, l4 = lane >> 4;

    // bijective XCD-aware swizzle: 4 unit-tiles (weight slabs) per XCD L2
    const int id = blockIdx.x;
    const int xcd = id & 7, slot = id >> 3;      // slot in [0,32)
    const int bx = xcd * 4 + (slot >> 3);        // [0,32) unit tile
    const int by = slot & 7;                     // [0,8)  batch tile
    const int u0 = bx << 5, b0 = by << 7;

    f32x4 acc[4][4] = {};                        // [gate][mi]

    // staging sources: 8 chunks per wave, chunk c = wave*8 + i
    const u16* src[8];
#pragma unroll
    for (int i = 0; i < 8; ++i) {
        const int c = wave * 8 + i;
        const int ks = c & 1;
        if (c < 16) {                            // A chunk, mf = c>>1
            const int mf = c >> 1;
            src[i] = A + (size_t)(b0 + mf * 16 + l15) * 1152 + ks * 32 + l4 * 8;
        } else {                                 // B chunk
            const int nf = (c - 16) >> 1, g = nf >> 1, us = nf & 1;
            src[i] = W + (size_t)(g * 1024 + u0 + us * 16 + l15) * ldw
                       + ks * 32 + l4 * 8;
        }
    }

#define STAGE(kt, bufi)                                                       \
    {                                                                         \
        const size_t ko = (size_t)(kt) * 64;                                  \
        _Pragma("unroll")                                                     \
        for (int i = 0; i < 8; ++i)                                           \
            gld16(src[i] + ko, (char*)&S[bufi][0] + ((wave * 8 + i) << 10));  \
    }

    const int nt = ntk - kt0;
    STAGE(kt0, 0);
    if (nt > 1) STAGE(kt0 + 1, 1);

    for (int t = 0; t < nt; ++t) {
        // own stage-t loads complete (oldest 8) BEFORE the barrier; stage t+1
        // stays in flight across it (counted vmcnt, T4).
        if (t + 1 < nt) asm volatile("s_waitcnt vmcnt(8)" ::: "memory");
        else            asm volatile("s_waitcnt vmcnt(0)" ::: "memory");
        __builtin_amdgcn_sched_barrier(0);
        __builtin_amdgcn_s_barrier();
        __builtin_amdgcn_sched_barrier(0);
        if (t + 2 < nt) STAGE(kt0 + t + 2, (t + 2) % 3);

        const char* Sb = (const char*)&S[t % 3][0];
#pragma unroll
        for (int ks = 0; ks < 2; ++ks) {
            bf16x8 af[4], bfr[4];
#pragma unroll
            for (int mi = 0; mi < 4; ++mi)
                af[mi] = *(const bf16x8*)(Sb +
                         ((((wm * 4 + mi) * 2 + ks) << 10) + (lane << 4)));
#pragma unroll
            for (int g = 0; g < 4; ++g)
                bfr[g] = *(const bf16x8*)(Sb +
                         (((16 + (g * 2 + wn) * 2 + ks) << 10) + (lane << 4)));
#pragma unroll
            for (int g = 0; g < 4; ++g)
#pragma unroll
                for (int mi = 0; mi < 4; ++mi)
                    acc[g][mi] = mfma16(af[mi], bfr[g], acc[g][mi]);
        }
    }
#undef STAGE

    // epilogue: LSTM pointwise update
    const int u = u0 + wn * 16 + l15;
    const float bi = bias[u],        bff = bias[1024 + u],
                bg = bias[2048 + u], bo  = bias[3072 + u];
#pragma unroll
    for (int mi = 0; mi < 4; ++mi) {
#pragma unroll
        for (int j = 0; j < 4; ++j) {
            const int b = b0 + wm * 64 + mi * 16 + l4 * 4 + j;
            const size_t ci = (size_t)b * 1024 + u;
            const float cold = cst[ci];
            const float xi = acc[0][mi][j] + bi;
            const float xf = acc[1][mi][j] + bff;
            const float xg = acc[2][mi][j] + bg;
            const float xo = acc[3][mi][j] + bo;
            const float cn = sigm(xf) * cold + sigm(xi) * tanh_(xg);
            const float hn = sigm(xo) * tanh_(cn);
            cst[ci] = cn;
            const u16 hb = f2bf(hn);
            Aout[(size_t)b * 1152 + u] = hb;
            if (hall) hall[(size_t)b * 1024 + u] = hb;
        }
    }

    // encoder: stage v_{t+1} (bf16) into the v-slot of the next-step input
    if (vsrc != nullptr && bx == 0) {
        for (int s = tid; s < 4096; s += 256) {
            const int bl = s >> 5, f4 = s & 31;
            const float4 vv = *(const float4*)(vsrc + (size_t)(b0 + bl) * 8192 + f4 * 4);
            ushort4 ov = make_ushort4(f2bf(vv.x), f2bf(vv.y), f2bf(vv.z), f2bf(vv.w));
            *(ushort4*)(Aout + (size_t)(b0 + bl) * 1152 + 1024 + f4 * 4) = ov;
        }
    }
}

// ---------------------------------------------------------------------------
// Regression GEMM: C[M][128] = A[M][lda(first 1024 cols)] @ Wreg[128][1024]^T
// 128x128 tile per block, M = grid*128.
// ---------------------------------------------------------------------------
__global__ __launch_bounds__(256)
void gemm_nt(const u16* __restrict__ A, int lda,
             const u16* __restrict__ Bw, float* __restrict__ C)
{
    __shared__ __align__(16) u16 As[128 * 64];   // 16 KB
    __shared__ __align__(16) u16 Bs[128 * 64];   // 16 KB
    const int tid = threadIdx.x, lane = tid & 63, wave = tid >> 6;
    const int wm = wave >> 1, wn = wave & 1;
    const int l15 = lane & 15, l4 = lane >> 4;
    const size_t row0 = (size_t)blockIdx.x * 128;

    f32x4 acc[4][4] = {};
    const u16* asrc[4];
    const u16* bsrc[4];
#pragma unroll
    for (int i = 0; i < 4; ++i) {
        int fi = i * 4 + wave;                   // [0,16)
        int ks = fi >> 3, rib = fi & 7;
        int r = rib * 16 + l15, k = ks * 32 + l4 * 8;
        asrc[i] = A + (row0 + r) * (size_t)lda + k;
        bsrc[i] = Bw + (size_t)r * 1024 + k;
    }
    for (int kt = 0; kt < 16; ++kt) {
#pragma unroll
        for (int i = 0; i < 4; ++i) {
            gld16(asrc[i] + kt * 64, (char*)As + ((i * 256 + wave * 64) << 4));
            gld16(bsrc[i] + kt * 64, (char*)Bs + ((i * 256 + wave * 64) << 4));
        }
        __syncthreads();
#pragma unroll
        for (int ks = 0; ks < 2; ++ks) {
            bf16x8 af[4], bfr[4];
#pragma unroll
            for (int t = 0; t < 4; ++t) {
                af[t]  = *(const bf16x8*)((const char*)As + (((ks * 8 + wm * 4 + t) * 64 + lane) << 4));
                bfr[t] = *(const bf16x8*)((const char*)Bs + (((ks * 8 + wn * 4 + t) * 64 + lane) << 4));
            }
#pragma unroll
            for (int mi = 0; mi < 4; ++mi)
#pragma unroll
                for (int ni = 0; ni < 4; ++ni)
                    acc[mi][ni] = mfma16(af[mi], bfr[ni], acc[mi][ni]);
        }
        __syncthreads();
    }
#pragma unroll
    for (int mi = 0; mi < 4; ++mi)
#pragma unroll
        for (int ni = 0; ni < 4; ++ni) {
            const int r = wm * 64 + mi * 16 + l4 * 4;
            const int cc = wn * 64 + ni * 16 + l15;
#pragma unroll
            for (int j = 0; j < 4; ++j)
                C[(row0 + r + j) * 128 + cc] = acc[mi][ni][j];
        }
}

// --------------------------- small kernels ---------------------------------

// out[k] = x_last + prefix_k(Vall + b_reg); Vall aliases out (in-place safe).
__global__ __launch_bounds__(256)
void scan_out(const float* __restrict__ Vall, const float* __restrict__ x,
              const float* __restrict__ breg, float* __restrict__ out)
{
    const int idx = blockIdx.x * 256 + threadIdx.x;   // 131072 = B*F
    const int b = idx >> 7, f = idx & 127;
    const float br = breg[f];
    float acc = x[(size_t)b * 4096 + 31 * 128 + f];   // x[:, -1, :]
    for (int k = 0; k < 64; ++k) {
        acc += Vall[(size_t)k * 131072 + idx] + br;
        out[(size_t)k * 131072 + idx] = acc;
    }
}

__global__ __launch_bounds__(256)
void transpose_y(const float* __restrict__ y, float* __restrict__ out2)
{
    const int idx = blockIdx.x * 256 + threadIdx.x;   // 2,097,152 float4 slots
    const int f4 = idx & 31;
    const int rest = idx >> 5;
    const int b = rest & 1023, p = rest >> 10;
    const float4 vv = *(const float4*)(y + ((size_t)b * 64 + p) * 128 + f4 * 4);
    *(float4*)(out2 + ((size_t)p * 1024 + b) * 128 + f4 * 4) = vv;
}

__global__ __launch_bounds__(256)
void conv_wcat(const float* __restrict__ Whh, const float* __restrict__ Wih,
               u16* __restrict__ Wcat)
{
    const int idx = blockIdx.x * 256 + threadIdx.x;   // 4096*288 float4 slots
    const int j = idx / 288, r = idx % 288;
    const float4 vv = (r < 256)
        ? *(const float4*)(Whh + (size_t)j * 1024 + r * 4)
        : *(const float4*)(Wih + (size_t)j * 128 + (r - 256) * 4);
    ushort4 ov = make_ushort4(f2bf(vv.x), f2bf(vv.y), f2bf(vv.z), f2bf(vv.w));
    *(ushort4*)(Wcat + (size_t)j * 1152 + r * 4) = ov;
}

__global__ __launch_bounds__(256)
void conv_wreg(const float* __restrict__ Wreg, u16* __restrict__ Wregb)
{
    const int idx = blockIdx.x * 256 + threadIdx.x;   // 32768 float4 slots
    const float4 vv = *(const float4*)(Wreg + (size_t)idx * 4);
    ushort4 ov = make_ushort4(f2bf(vv.x), f2bf(vv.y), f2bf(vv.z), f2bf(vv.w));
    *(ushort4*)(Wregb + (size_t)idx * 4) = ov;
}

// W_dec = W_hh + W_ih @ W_reg (f32, bf16 store); also bcomb = b_ih+b_hh and
// b_dec = bcomb + W_ih @ b_reg. Grid 1024: 256 j-tiles x 4 u-tiles; 16 acc
// registers per thread (no spill).
__global__ __launch_bounds__(256)
void prep_wdec(const float* __restrict__ Whh, const float* __restrict__ Wih,
               const float* __restrict__ Wreg, const float* __restrict__ bih,
               const float* __restrict__ bhh, const float* __restrict__ breg,
               u16* __restrict__ Wdec, float* __restrict__ bcomb,
               float* __restrict__ bdec)
{
    __shared__ float wih[16][128];                    // 8 KB
    const int jt = blockIdx.x >> 2, ut = blockIdx.x & 3;
    const int j0 = jt * 16;
    const int u = ut * 256 + threadIdx.x;
    for (int s = threadIdx.x; s < 2048; s += 256)
        wih[s >> 7][s & 127] = Wih[(size_t)(j0 + (s >> 7)) * 128 + (s & 127)];
    __syncthreads();
    float acc[16];
#pragma unroll
    for (int j = 0; j < 16; ++j) acc[j] = Whh[(size_t)(j0 + j) * 1024 + u];
    for (int f = 0; f < 128; ++f) {
        const float wr = Wreg[(size_t)f * 1024 + u];
#pragma unroll
        for (int j = 0; j < 16; ++j) acc[j] += wih[j][f] * wr;
    }
#pragma unroll
    for (int j = 0; j < 16; ++j)
        Wdec[(size_t)(j0 + j) * 1024 + u] = f2bf(acc[j]);
    if (ut == 0 && threadIdx.x < 16) {
        const int j = j0 + threadIdx.x;
        float a = bih[j] + bhh[j];
        bcomb[j] = a;
        for (int f = 0; f < 128; ++f) a += wih[threadIdx.x][f] * breg[f];
        bdec[j] = a;
    }
}

__global__ __launch_bounds__(256)
void init_acat(const float* __restrict__ v, u16* __restrict__ Acat)
{
    const int idx = blockIdx.x * 256 + threadIdx.x;   // 32768 float4 slots
    const int b = idx >> 5, f4 = idx & 31;
    const float4 vv = *(const float4*)(v + (size_t)b * 8192 + f4 * 4);
    ushort4 ov = make_ushort4(f2bf(vv.x), f2bf(vv.y), f2bf(vv.z), f2bf(vv.w));
    *(ushort4*)(Acat + (size_t)b * 1152 + 1024 + f4 * 4) = ov;
}

// ---------------------------------------------------------------------------

extern "C" void kernel_launch(void* const* d_in, const int* in_sizes, int n_in,
                              void* d_out, int out_size, void* d_ws, size_t ws_size,
                              hipStream_t stream)
{
    const float* x    = (const float*)d_in[0];
    const float* y    = (const float*)d_in[1];
    const float* v    = (const float*)d_in[2];
    const float* Wih  = (const float*)d_in[3];
    const float* Whh  = (const float*)d_in[4];
    const float* bih  = (const float*)d_in[5];
    const float* bhh  = (const float*)d_in[6];
    const float* Wreg = (const float*)d_in[7];
    const float* breg = (const float*)d_in[8];
    float* out = (float*)d_out;
    char* ws = (char*)d_ws;

    u16*   Wcat  = (u16*)(ws + 0);              //  9,437,184  [4096][1152] bf16
    u16*   Wdec  = (u16*)(ws + 9437184);        //  8,388,608  [4096][1024] bf16
    u16*   Wregb = (u16*)(ws + 17825792);       //    262,144  [128][1024] bf16
    float* bcomb = (float*)(ws + 18087936);     //     16,384
    float* bdec  = (float*)(ws + 18104320);     //     16,384
    u16*   Ac0   = (u16*)(ws + 18120704);       //  2,359,296  [1024][1152] bf16
    u16*   Ac1   = (u16*)(ws + 20480000);       //  2,359,296
    float* cst   = (float*)(ws + 22839296);     //  4,194,304  [1024][1024] f32
    u16*   Hall  = (u16*)(ws + 27033600);       //134,217,728  [64][1024][1024] bf16
    float* Vall  = out;                         // aliases output region (33.5 MB)
    u16* Ac[2] = {Ac0, Ac1};

    const bool batched = ws_size >= (size_t)27033600 + 134217728;

    hipMemsetAsync(cst, 0, 4194304, stream);    // c0 = 0
    hipMemsetAsync(Ac0, 0, 2359296, stream);    // h0 = 0 (bf16 zero bits)
    prep_wdec<<<1024, 256, 0, stream>>>(Whh, Wih, Wreg, bih, bhh, breg,
                                        Wdec, bcomb, bdec);
    conv_wcat<<<4608, 256, 0, stream>>>(Whh, Wih, Wcat);
    conv_wreg<<<128, 256, 0, stream>>>(Wreg, Wregb);
    init_acat<<<128, 256, 0, stream>>>(v, Ac0);
    transpose_y<<<8192, 256, 0, stream>>>(y, out + 8388608);

    // encoder: 64 steps, K = 1152 ([h | v_t] @ [W_hh | W_ih]^T).
    // t=0 has h==0, so only the v columns (K-tiles 16..17) are computed.
    for (int t = 0; t < 64; ++t) {
        lstm_step<<<256, 256, 0, stream>>>(
            Ac[t & 1], Wcat, 1152, (t == 0) ? 16 : 0, 18, bcomb, cst,
            Ac[(t + 1) & 1],
            (batched && t == 63) ? Hall : (u16*)nullptr,
            (t < 63) ? (v + (size_t)(t + 1) * 128) : (const float*)nullptr);
    }
    if (!batched)   // Vall[0] = h_0 @ W_reg^T
        gemm_nt<<<8, 256, 0, stream>>>(Ac[0], 1152, Wregb, Vall);

    // decoder: 63 steps, K = 1024 (h @ W_dec^T)
    for (int k = 1; k < 64; ++k) {
        lstm_step<<<256, 256, 0, stream>>>(
            Ac[(k + 1) & 1], Wdec, 1024, 0, 16, bdec, cst, Ac[k & 1],
            batched ? (Hall + (size_t)k * 1048576) : (u16*)nullptr,
            (const float*)nullptr);
        if (!batched)
            gemm_nt<<<8, 256, 0, stream>>>(Ac[k & 1], 1152, Wregb,
                                           Vall + (size_t)k * 131072);
    }
    if (batched)    // Vall[k][b][:] = h_k @ W_reg^T  (one GEMM, M=65536)
        gemm_nt<<<512, 256, 0, stream>>>(Hall, 1024, Wregb, Vall);

    // out[k] = x_last + prefix_sum(Vall + b_reg)
    scan_out<<<512, 256, 0, stream>>>(Vall, x, breg, out);
}